// Round 2
// baseline (10022.527 us; speedup 1.0000x reference)
//
#include <hip/hip_runtime.h>

// MatchLSTM forward (Round 17): phase B GEMVs moved to MFMA.
//   Phase B was VALU-issue-bound (R16 counters: MfmaUtil 0, VALUBusy 40%
//   over 256 CUs = ~80% on the 128 active CUs; HBM 0.4%). The two per-step
//   GEMVs (Wm 512x512, W3 1536x512 = 1.05M MAC/step/block) now run as
//   16x16x32 bf16 MFMA with BROADCAST-A: the activation vector is splatted
//   into all 16 A rows (row-layout-immune), weights are B-frags from a new
//   row-major bf16 pack. Activations split hi/lo bf16 (2 MFMAs) to keep
//   fp32-act precision. New floor: L2 weight re-read, 16.4 GB ~ 540 us.
// Phase A: Round-15 verbatim (validated).

#define DEV static __device__ __forceinline__

DEV float fast_sigmoid(float x) { return 1.0f / (1.0f + __expf(-x)); }
DEV float fast_tanh(float x)    { return 1.0f - 2.0f / (__expf(2.0f * x) + 1.0f); }

DEV unsigned f2bf(float x) {
    unsigned v = __float_as_uint(x);
    return (v + 0x7FFFu + ((v >> 16) & 1u)) >> 16;
}
DEV float blo(unsigned u) { return __uint_as_float(u << 16); }

DEV float ntload(const float* p) { return __builtin_nontemporal_load(p); }

typedef __attribute__((ext_vector_type(8))) short bfrag;   // 8 bf16
typedef __attribute__((ext_vector_type(4))) float ffrag;   // 4 fp32 acc

DEV void cvt_hilo(const float* v, bfrag& hi, bfrag& lo)
{
#pragma unroll
    for (int z = 0; z < 8; ++z) {
        unsigned h = f2bf(v[z]);
        hi[z] = (short)h;
        lo[z] = (short)f2bf(v[z] - __uint_as_float(h << 16));
    }
}

// ---------------------------------------------------------------------------
// MFMA GEMM (validated R14): C[M][512] = A[M][512] . W[512][512]^T, bf16x3.
// ---------------------------------------------------------------------------
__global__ __launch_bounds__(256) void mfma_nt_kernel(
    const float* __restrict__ A, const float* __restrict__ W,
    float* __restrict__ C)
{
    const int wv   = threadIdx.x >> 6;
    const int lane = threadIdx.x & 63;
    const int row  = lane & 15;
    const int quad = lane >> 4;
    const int m0 = blockIdx.x * 64 + wv * 16;
    const int n0 = blockIdx.y * 64;

    ffrag acc[4];
#pragma unroll
    for (int n = 0; n < 4; ++n)
#pragma unroll
        for (int r = 0; r < 4; ++r) acc[n][r] = 0.0f;

    for (int k0 = 0; k0 < 512; k0 += 32) {
        const float* ap = A + (size_t)(m0 + row) * 512 + k0 + quad * 8;
        float4 aA = *(const float4*)ap;
        float4 aB = *(const float4*)(ap + 4);
        float av[8] = {aA.x, aA.y, aA.z, aA.w, aB.x, aB.y, aB.z, aB.w};
        bfrag ahi, alo;
        cvt_hilo(av, ahi, alo);
#pragma unroll
        for (int n = 0; n < 4; ++n) {
            const float* wp = W + (size_t)(n0 + n * 16 + row) * 512 + k0 + quad * 8;
            float4 wA = *(const float4*)wp;
            float4 wB = *(const float4*)(wp + 4);
            float wvv[8] = {wA.x, wA.y, wA.z, wA.w, wB.x, wB.y, wB.z, wB.w};
            bfrag whi, wlo;
            cvt_hilo(wvv, whi, wlo);
            acc[n] = __builtin_amdgcn_mfma_f32_16x16x32_bf16(ahi, whi, acc[n], 0, 0, 0);
            acc[n] = __builtin_amdgcn_mfma_f32_16x16x32_bf16(alo, whi, acc[n], 0, 0, 0);
            acc[n] = __builtin_amdgcn_mfma_f32_16x16x32_bf16(ahi, wlo, acc[n], 0, 0, 0);
        }
    }
#pragma unroll
    for (int n = 0; n < 4; ++n)
#pragma unroll
        for (int r = 0; r < 4; ++r)
            C[(size_t)(m0 + quad * 4 + r) * 512 + n0 + n * 16 + row] = acc[n][r];
}

// ---------------------------------------------------------------------------
// 3-gate MFMA GEMM (validated R15).
// ---------------------------------------------------------------------------
template<int GATHER>
__global__ __launch_bounds__(256) void mfma_g3_kernel(
    const float* __restrict__ A, const int* __restrict__ gidx,
    int lda, int K,
    const float* __restrict__ W, int ldw,
    const float* __restrict__ bias1, const float* __restrict__ bias2,
    float* __restrict__ out)
{
    const int wv   = threadIdx.x >> 6;
    const int lane = threadIdx.x & 63;
    const int row  = lane & 15;
    const int quad = lane >> 4;
    const int m0   = blockIdx.x * 64 + wv * 16;
    const int gate = blockIdx.y >> 3;
    const int gbase = (gate == 0) ? 0 : (gate == 1 ? 1024 : 1536);
    const int j0   = (blockIdx.y & 7) * 64;

    const int arow = GATHER ? gidx[m0 + row] : (m0 + row);

    ffrag acc[4];
#pragma unroll
    for (int n = 0; n < 4; ++n)
#pragma unroll
        for (int r = 0; r < 4; ++r) acc[n][r] = 0.0f;

    for (int k0 = 0; k0 < K; k0 += 32) {
        const bool tail = (k0 + 32 > K);
        float av[8];
        if (!tail) {
            const float* ap = A + (size_t)arow * lda + k0 + quad * 8;
            float4 aA = *(const float4*)ap;
            float4 aB = *(const float4*)(ap + 4);
            av[0]=aA.x; av[1]=aA.y; av[2]=aA.z; av[3]=aA.w;
            av[4]=aB.x; av[5]=aB.y; av[6]=aB.z; av[7]=aB.w;
        } else {
#pragma unroll
            for (int z = 0; z < 8; ++z) {
                int kk = k0 + quad * 8 + z;
                av[z] = (kk < K) ? A[(size_t)arow * lda + kk] : 0.0f;
            }
        }
        bfrag ahi, alo;
        cvt_hilo(av, ahi, alo);
#pragma unroll
        for (int n = 0; n < 4; ++n) {
            const int wrow = gbase + j0 + n * 16 + row;
            float wvv[8];
            if (!tail) {
                const float* wp = W + (size_t)wrow * ldw + k0 + quad * 8;
                float4 wA = *(const float4*)wp;
                float4 wB = *(const float4*)(wp + 4);
                wvv[0]=wA.x; wvv[1]=wA.y; wvv[2]=wA.z; wvv[3]=wA.w;
                wvv[4]=wB.x; wvv[5]=wB.y; wvv[6]=wB.z; wvv[7]=wB.w;
            } else {
#pragma unroll
                for (int z = 0; z < 8; ++z) {
                    int kk = k0 + quad * 8 + z;
                    wvv[z] = (kk < K) ? W[(size_t)wrow * ldw + kk] : 0.0f;
                }
            }
            bfrag whi, wlo;
            cvt_hilo(wvv, whi, wlo);
            acc[n] = __builtin_amdgcn_mfma_f32_16x16x32_bf16(ahi, whi, acc[n], 0, 0, 0);
            acc[n] = __builtin_amdgcn_mfma_f32_16x16x32_bf16(alo, whi, acc[n], 0, 0, 0);
            acc[n] = __builtin_amdgcn_mfma_f32_16x16x32_bf16(ahi, wlo, acc[n], 0, 0, 0);
        }
    }
#pragma unroll
    for (int n = 0; n < 4; ++n) {
        const int j = j0 + n * 16 + row;
        const float bb = bias1[gbase + j] + bias2[gbase + j];
#pragma unroll
        for (int r = 0; r < 4; ++r) {
            const int m = m0 + quad * 4 + r;
            out[((size_t)m * 3 + gate) * 512 + j] = acc[n][r] + bb;
        }
    }
}

// ---------------------------------------------------------------------------
// Encoder gate math (validated R15).
// ---------------------------------------------------------------------------
__global__ __launch_bounds__(256) void enc_gates_kernel(
    const float* __restrict__ P, float* __restrict__ h)
{
    const int i = blockIdx.x * 256 + threadIdx.x;
    const int m = i >> 7;
    const int j4 = (i & 127) * 4;
    const float* p = P + (size_t)m * 1536 + j4;
    float4 gi = *(const float4*)p;
    float4 gg = *(const float4*)(p + 512);
    float4 go = *(const float4*)(p + 1024);
    float4 r;
    r.x = fast_sigmoid(go.x) * fast_tanh(fast_sigmoid(gi.x) * fast_tanh(gg.x));
    r.y = fast_sigmoid(go.y) * fast_tanh(fast_sigmoid(gi.y) * fast_tanh(gg.y));
    r.z = fast_sigmoid(go.z) * fast_tanh(fast_sigmoid(gi.z) * fast_tanh(gg.z));
    r.w = fast_sigmoid(go.w) * fast_tanh(fast_sigmoid(gi.w) * fast_tanh(gg.w));
    *(float4*)&h[(size_t)m * 512 + j4] = r;
}

// ---------------------------------------------------------------------------
// NEW: row-major bf16 weight pack for phase-B MFMA B-fragments.
//   WmB [512][512]  bf16 <- Wm (512x512 fp32, rows = outputs)
//   W3B [1536][512] bf16 <- Wih_m rows {i:0-511, g:1024-1535, o:1536-2047},
//                           cols 0..511 (a_k part; h_t part is pre_m_h).
// Stored as uint (2 bf16/uint), row stride 256 uints = 1 KB.
// ---------------------------------------------------------------------------
__global__ __launch_bounds__(256) void pack_bf16_kernel(
    const float* __restrict__ Wm, const float* __restrict__ W3,
    unsigned* __restrict__ WmB, unsigned* __restrict__ W3B)
{
    int i = blockIdx.x * 256 + threadIdx.x;           // 0 .. 524287
    if (i < 512 * 256) {
        int r = i >> 8, c = (i & 255) * 2;
        unsigned lo = f2bf(Wm[(size_t)r * 512 + c]);
        unsigned hi = f2bf(Wm[(size_t)r * 512 + c + 1]);
        WmB[(size_t)r * 256 + (c >> 1)] = lo | (hi << 16);
    } else {
        i -= 512 * 256;
        int r = i >> 8, c = (i & 255) * 2;
        int gate = r >> 9;
        int src  = (gate == 0 ? 0 : (gate == 1 ? 1024 : 1536)) + (r & 511);
        unsigned lo = f2bf(W3[(size_t)src * 1024 + c]);
        unsigned hi = f2bf(W3[(size_t)src * 1024 + c + 1]);
        W3B[(size_t)r * 256 + (c >> 1)] = lo | (hi << 16);
    }
}

// ---------------------------------------------------------------------------
// Phase B (Round 17): GEMVs on the matrix pipe.
//   Broadcast-A MFMA: all 16 A-rows carry the same activation slice, so the
//   result is independent of the A row mapping; C col = lane&15 (validated),
//   any m-row works -> read quad 0, reg 0. B-frags: lane reads 16B of row
//   (ntile*16 + lane&15) at k-offset (lane>>4)*8 -> same k-mapping as the
//   validated mfma_nt load. Activations hi/lo bf16 (2 MFMA) ~ fp32 precision.
// ---------------------------------------------------------------------------
__global__ __launch_bounds__(1024) void phaseB_kernel(
    const float* __restrict__ pre_s, const float* __restrict__ pre_t,
    const float* __restrict__ h_s,   const float* __restrict__ pre_m_h,
    const unsigned* __restrict__ WmB, const unsigned* __restrict__ W3B,
    const float* __restrict__ w_e,
    const float* __restrict__ fc_w,  const float* __restrict__ fc_b,
    float* __restrict__ out)
{
    __shared__ __align__(16) float hm[512];
    __shared__ __align__(16) float base[512];
    __shared__ __align__(16) float wesh[512];
    __shared__ __align__(16) float sc[64];
    __shared__ __align__(16) float red[2 * 512];
    __shared__ __align__(16) float gates3[1536];
    __shared__ __align__(16) unsigned short hmh[512];
    __shared__ __align__(16) unsigned short hml[512];
    __shared__ __align__(16) unsigned short avh[512];
    __shared__ __align__(16) unsigned short avl[512];

    const int b    = blockIdx.x;
    const int tid  = threadIdx.x;
    const int wv   = tid >> 6;
    const int lane = tid & 63;
    const int j    = tid & 511;
    const int kh   = tid >> 9;
    const int col  = lane & 15;
    const int quad = lane >> 4;

    if (tid < 512) {
        wesh[tid] = w_e[tid];
        hm[tid] = 0.0f; hmh[tid] = 0; hml[tid] = 0;
    }
    __syncthreads();

    for (int k = 0; k < 64; ++k) {
        // ---- GEMV1: base = pre_t[k,b,:] + Wm . hm  (hm==0 at k==0: acc=0)
#pragma unroll
        for (int t = 0; t < 2; ++t) {
            const int nt = wv * 2 + t;                 // 0..31
            ffrag acc = {0.0f, 0.0f, 0.0f, 0.0f};
            const unsigned* wrow = WmB + (size_t)(nt * 16 + col) * 256;
            for (int k0 = 0; k0 < 512; k0 += 32) {
                bfrag ah = *(const bfrag*)&hmh[k0 + quad * 8];
                bfrag al = *(const bfrag*)&hml[k0 + quad * 8];
                bfrag wb = *(const bfrag*)(wrow + (k0 >> 1) + quad * 4);
                acc = __builtin_amdgcn_mfma_f32_16x16x32_bf16(ah, wb, acc, 0, 0, 0);
                acc = __builtin_amdgcn_mfma_f32_16x16x32_bf16(al, wb, acc, 0, 0, 0);
            }
            if (lane < 16)
                base[nt * 16 + lane] = acc[0]
                    + ntload(&pre_t[((size_t)k * 128 + b) * 512 + nt * 16 + lane]);
        }
        __syncthreads();

        // ---- attention scores: e[t] = w_e . tanh(pre_s[t] + base)
#pragma unroll
        for (int tt = 0; tt < 4; ++tt) {
            int t = wv * 4 + tt;
            const float* ps = pre_s + ((size_t)t * 128 + b) * 512;
            float p = 0.0f;
#pragma unroll
            for (int u = 0; u < 8; ++u) {
                int h = lane + 64 * u;
                p += wesh[h] * fast_tanh(ntload(&ps[h]) + base[h]);
            }
#pragma unroll
            for (int off = 32; off; off >>= 1) p += __shfl_xor(p, off);
            if (lane == 0) sc[t] = p;
        }
        __syncthreads();

        // ---- softmax over 64 premise positions
        if (wv == 0) {
            float s = sc[lane], mx = s;
#pragma unroll
            for (int off = 32; off; off >>= 1) mx = fmaxf(mx, __shfl_xor(mx, off));
            float e = __expf(s - mx), sum = e;
#pragma unroll
            for (int off = 32; off; off >>= 1) sum += __shfl_xor(sum, off);
            sc[lane] = e / sum;
        }
        __syncthreads();

        // ---- a_k = sum_t alpha[t] * h_s[t,b,:]   (kh-split + LDS reduce)
        {
            const float* hp = h_s + (size_t)b * 512 + j;
            float p = 0.0f;
#pragma unroll
            for (int t4 = 0; t4 < 8; ++t4) {
                int t = kh * 32 + t4 * 4;
                float4 s4 = *(const float4*)&sc[t];
                p += s4.x * ntload(&hp[(size_t)(t + 0) * 65536])
                   + s4.y * ntload(&hp[(size_t)(t + 1) * 65536])
                   + s4.z * ntload(&hp[(size_t)(t + 2) * 65536])
                   + s4.w * ntload(&hp[(size_t)(t + 3) * 65536]);
            }
            red[kh * 512 + j] = p;
        }
        __syncthreads();
        if (tid < 512) {
            float a = red[tid] + red[512 + tid];
            unsigned h = f2bf(a);
            avh[tid] = (unsigned short)h;
            avl[tid] = (unsigned short)f2bf(a - blo(h));
        }
        __syncthreads();

        // ---- GEMV2: gates3[1536] = W3 . a_k
#pragma unroll
        for (int t = 0; t < 6; ++t) {
            const int nt = wv * 6 + t;                 // 0..95
            ffrag acc = {0.0f, 0.0f, 0.0f, 0.0f};
            const unsigned* wrow = W3B + (size_t)(nt * 16 + col) * 256;
            for (int k0 = 0; k0 < 512; k0 += 32) {
                bfrag ah = *(const bfrag*)&avh[k0 + quad * 8];
                bfrag al = *(const bfrag*)&avl[k0 + quad * 8];
                bfrag wb = *(const bfrag*)(wrow + (k0 >> 1) + quad * 4);
                acc = __builtin_amdgcn_mfma_f32_16x16x32_bf16(ah, wb, acc, 0, 0, 0);
                acc = __builtin_amdgcn_mfma_f32_16x16x32_bf16(al, wb, acc, 0, 0, 0);
            }
            if (lane < 16) gates3[nt * 16 + lane] = acc[0];
        }
        __syncthreads();

        // ---- gate math -> hm (+ hi/lo pack for next step's GEMV1)
        if (tid < 512) {
            const size_t m = (size_t)k * 128 + b;
            float gi = gates3[tid]        + ntload(&pre_m_h[(m * 3 + 0) * 512 + tid]);
            float gg = gates3[512 + tid]  + ntload(&pre_m_h[(m * 3 + 1) * 512 + tid]);
            float go = gates3[1024 + tid] + ntload(&pre_m_h[(m * 3 + 2) * 512 + tid]);
            float cc = fast_sigmoid(gi) * fast_tanh(gg);
            float hv = fast_sigmoid(go) * fast_tanh(cc);
            hm[tid] = hv;
            unsigned hb = f2bf(hv);
            hmh[tid] = (unsigned short)hb;
            hml[tid] = (unsigned short)f2bf(hv - blo(hb));
        }
        __syncthreads();
    }

    if (wv < 3) {
        float p = 0.0f;
#pragma unroll
        for (int u = 0; u < 8; ++u) {
            int h = lane + 64 * u;
            p += hm[h] * fc_w[wv * 512 + h];
        }
#pragma unroll
        for (int off = 32; off; off >>= 1) p += __shfl_xor(p, off);
        if (lane == 0) out[b * 3 + wv] = p + fc_b[wv];
    }
}

extern "C" void kernel_launch(void* const* d_in, const int* in_sizes, int n_in,
                              void* d_out, int out_size, void* d_ws, size_t ws_size,
                              hipStream_t stream)
{
    (void)in_sizes; (void)n_in; (void)out_size;
    const int*   premise    = (const int*)d_in[0];
    const int*   hypothesis = (const int*)d_in[2];
    const float* embed  = (const float*)d_in[4];
    const float* w_e    = (const float*)d_in[5];
    const float* Ws     = (const float*)d_in[6];
    const float* Wt     = (const float*)d_in[7];
    const float* Wm     = (const float*)d_in[8];
    const float* Wih_p  = (const float*)d_in[9];
    const float* bih_p  = (const float*)d_in[10];
    const float* bhh_p  = (const float*)d_in[11];
    const float* Wih_h  = (const float*)d_in[12];
    const float* bih_h  = (const float*)d_in[13];
    const float* bhh_h  = (const float*)d_in[14];
    const float* Wih_m  = (const float*)d_in[15];
    const float* bih_m  = (const float*)d_in[16];
    const float* bhh_m  = (const float*)d_in[17];
    const float* fc_w   = (const float*)d_in[18];
    const float* fc_b   = (const float*)d_in[19];

    float* ws      = (float*)d_ws;
    float* h_s     = ws;                      // 8192*512
    float* h_t     = h_s    + 4194304;        // 8192*512 (aliased by packs)
    float* pre_s   = h_t    + 4194304;
    float* pre_t   = pre_s  + 4194304;
    float* pre_m_h = pre_t  + 4194304;        // 8192*3*512 (+ encoder scratch)
    unsigned* WmB  = (unsigned*)h_t;          // aliases h_t after last reader
    unsigned* W3B  = WmB + 131072;            // 512KB + 1.5MB << 16MB region
    float* outp    = (float*)d_out;
    if (ws_size < (size_t)29556736 * 4) return;

    dim3 blk(256);
    float* P = pre_m_h;                       // encoder preact scratch

    // Phase A (all MFMA, validated)
    mfma_g3_kernel<1><<<dim3(128, 24), blk, 0, stream>>>(
        embed, premise, 300, 300, Wih_p, 300, bih_p, bhh_p, P);
    enc_gates_kernel<<<4096, blk, 0, stream>>>(P, h_s);
    mfma_g3_kernel<1><<<dim3(128, 24), blk, 0, stream>>>(
        embed, hypothesis, 300, 300, Wih_h, 300, bih_h, bhh_h, P);
    enc_gates_kernel<<<4096, blk, 0, stream>>>(P, h_t);
    mfma_nt_kernel<<<dim3(128, 8), blk, 0, stream>>>(h_s, Ws, pre_s);
    mfma_nt_kernel<<<dim3(128, 8), blk, 0, stream>>>(h_t, Wt, pre_t);
    mfma_g3_kernel<0><<<dim3(128, 24), blk, 0, stream>>>(
        h_t, nullptr, 512, 512, Wih_m + 512, 1024, bih_m, bhh_m, pre_m_h);

    // Weight pack (after h_t's last reader; output aliases h_t space)
    pack_bf16_kernel<<<2048, blk, 0, stream>>>(Wm, Wih_m, WmB, W3B);

    // Phase B (MFMA GEMVs)
    phaseB_kernel<<<dim3(128), dim3(1024), 0, stream>>>(
        pre_s, pre_t, h_s, pre_m_h, WmB, W3B, w_e, fc_w, fc_b, outp);
}

// Round 3
// 4692.862 us; speedup vs baseline: 2.1357x; 2.1357x over previous
//
#include <hip/hip_runtime.h>

// MatchLSTM forward (Round 18): R17 + spill fix.
//   R17 diagnosis: WRITE_SIZE 1.42 GB/dispatch (vs 4.6 MB in R16) with only
//   1.5 KB of real output = VGPR scratch spills. __launch_bounds__(1024)
//   pins 64 VGPRs; the un-annotated constant-trip k0 loops were fully
//   unrolled+pipelined by the compiler -> spill in the hot loop ->
//   latency-bound (MfmaUtil 2.3%). Fix = #pragma unroll 1 on GEMV loops
//   (same discipline R16's c0 loops used). MFMA path itself verified
//   correct in R17 (absmax bit-identical to R16).
// Phase A: Round-15 verbatim (validated).

#define DEV static __device__ __forceinline__

DEV float fast_sigmoid(float x) { return 1.0f / (1.0f + __expf(-x)); }
DEV float fast_tanh(float x)    { return 1.0f - 2.0f / (__expf(2.0f * x) + 1.0f); }

DEV unsigned f2bf(float x) {
    unsigned v = __float_as_uint(x);
    return (v + 0x7FFFu + ((v >> 16) & 1u)) >> 16;
}
DEV float blo(unsigned u) { return __uint_as_float(u << 16); }

DEV float ntload(const float* p) { return __builtin_nontemporal_load(p); }

typedef __attribute__((ext_vector_type(8))) short bfrag;   // 8 bf16
typedef __attribute__((ext_vector_type(4))) float ffrag;   // 4 fp32 acc

DEV void cvt_hilo(const float* v, bfrag& hi, bfrag& lo)
{
#pragma unroll
    for (int z = 0; z < 8; ++z) {
        unsigned h = f2bf(v[z]);
        hi[z] = (short)h;
        lo[z] = (short)f2bf(v[z] - __uint_as_float(h << 16));
    }
}

// ---------------------------------------------------------------------------
// MFMA GEMM (validated R14): C[M][512] = A[M][512] . W[512][512]^T, bf16x3.
// ---------------------------------------------------------------------------
__global__ __launch_bounds__(256) void mfma_nt_kernel(
    const float* __restrict__ A, const float* __restrict__ W,
    float* __restrict__ C)
{
    const int wv   = threadIdx.x >> 6;
    const int lane = threadIdx.x & 63;
    const int row  = lane & 15;
    const int quad = lane >> 4;
    const int m0 = blockIdx.x * 64 + wv * 16;
    const int n0 = blockIdx.y * 64;

    ffrag acc[4];
#pragma unroll
    for (int n = 0; n < 4; ++n)
#pragma unroll
        for (int r = 0; r < 4; ++r) acc[n][r] = 0.0f;

    for (int k0 = 0; k0 < 512; k0 += 32) {
        const float* ap = A + (size_t)(m0 + row) * 512 + k0 + quad * 8;
        float4 aA = *(const float4*)ap;
        float4 aB = *(const float4*)(ap + 4);
        float av[8] = {aA.x, aA.y, aA.z, aA.w, aB.x, aB.y, aB.z, aB.w};
        bfrag ahi, alo;
        cvt_hilo(av, ahi, alo);
#pragma unroll
        for (int n = 0; n < 4; ++n) {
            const float* wp = W + (size_t)(n0 + n * 16 + row) * 512 + k0 + quad * 8;
            float4 wA = *(const float4*)wp;
            float4 wB = *(const float4*)(wp + 4);
            float wvv[8] = {wA.x, wA.y, wA.z, wA.w, wB.x, wB.y, wB.z, wB.w};
            bfrag whi, wlo;
            cvt_hilo(wvv, whi, wlo);
            acc[n] = __builtin_amdgcn_mfma_f32_16x16x32_bf16(ahi, whi, acc[n], 0, 0, 0);
            acc[n] = __builtin_amdgcn_mfma_f32_16x16x32_bf16(alo, whi, acc[n], 0, 0, 0);
            acc[n] = __builtin_amdgcn_mfma_f32_16x16x32_bf16(ahi, wlo, acc[n], 0, 0, 0);
        }
    }
#pragma unroll
    for (int n = 0; n < 4; ++n)
#pragma unroll
        for (int r = 0; r < 4; ++r)
            C[(size_t)(m0 + quad * 4 + r) * 512 + n0 + n * 16 + row] = acc[n][r];
}

// ---------------------------------------------------------------------------
// 3-gate MFMA GEMM (validated R15).
// ---------------------------------------------------------------------------
template<int GATHER>
__global__ __launch_bounds__(256) void mfma_g3_kernel(
    const float* __restrict__ A, const int* __restrict__ gidx,
    int lda, int K,
    const float* __restrict__ W, int ldw,
    const float* __restrict__ bias1, const float* __restrict__ bias2,
    float* __restrict__ out)
{
    const int wv   = threadIdx.x >> 6;
    const int lane = threadIdx.x & 63;
    const int row  = lane & 15;
    const int quad = lane >> 4;
    const int m0   = blockIdx.x * 64 + wv * 16;
    const int gate = blockIdx.y >> 3;
    const int gbase = (gate == 0) ? 0 : (gate == 1 ? 1024 : 1536);
    const int j0   = (blockIdx.y & 7) * 64;

    const int arow = GATHER ? gidx[m0 + row] : (m0 + row);

    ffrag acc[4];
#pragma unroll
    for (int n = 0; n < 4; ++n)
#pragma unroll
        for (int r = 0; r < 4; ++r) acc[n][r] = 0.0f;

    for (int k0 = 0; k0 < K; k0 += 32) {
        const bool tail = (k0 + 32 > K);
        float av[8];
        if (!tail) {
            const float* ap = A + (size_t)arow * lda + k0 + quad * 8;
            float4 aA = *(const float4*)ap;
            float4 aB = *(const float4*)(ap + 4);
            av[0]=aA.x; av[1]=aA.y; av[2]=aA.z; av[3]=aA.w;
            av[4]=aB.x; av[5]=aB.y; av[6]=aB.z; av[7]=aB.w;
        } else {
#pragma unroll
            for (int z = 0; z < 8; ++z) {
                int kk = k0 + quad * 8 + z;
                av[z] = (kk < K) ? A[(size_t)arow * lda + kk] : 0.0f;
            }
        }
        bfrag ahi, alo;
        cvt_hilo(av, ahi, alo);
#pragma unroll
        for (int n = 0; n < 4; ++n) {
            const int wrow = gbase + j0 + n * 16 + row;
            float wvv[8];
            if (!tail) {
                const float* wp = W + (size_t)wrow * ldw + k0 + quad * 8;
                float4 wA = *(const float4*)wp;
                float4 wB = *(const float4*)(wp + 4);
                wvv[0]=wA.x; wvv[1]=wA.y; wvv[2]=wA.z; wvv[3]=wA.w;
                wvv[4]=wB.x; wvv[5]=wB.y; wvv[6]=wB.z; wvv[7]=wB.w;
            } else {
#pragma unroll
                for (int z = 0; z < 8; ++z) {
                    int kk = k0 + quad * 8 + z;
                    wvv[z] = (kk < K) ? W[(size_t)wrow * ldw + kk] : 0.0f;
                }
            }
            bfrag whi, wlo;
            cvt_hilo(wvv, whi, wlo);
            acc[n] = __builtin_amdgcn_mfma_f32_16x16x32_bf16(ahi, whi, acc[n], 0, 0, 0);
            acc[n] = __builtin_amdgcn_mfma_f32_16x16x32_bf16(alo, whi, acc[n], 0, 0, 0);
            acc[n] = __builtin_amdgcn_mfma_f32_16x16x32_bf16(ahi, wlo, acc[n], 0, 0, 0);
        }
    }
#pragma unroll
    for (int n = 0; n < 4; ++n) {
        const int j = j0 + n * 16 + row;
        const float bb = bias1[gbase + j] + bias2[gbase + j];
#pragma unroll
        for (int r = 0; r < 4; ++r) {
            const int m = m0 + quad * 4 + r;
            out[((size_t)m * 3 + gate) * 512 + j] = acc[n][r] + bb;
        }
    }
}

// ---------------------------------------------------------------------------
// Encoder gate math (validated R15).
// ---------------------------------------------------------------------------
__global__ __launch_bounds__(256) void enc_gates_kernel(
    const float* __restrict__ P, float* __restrict__ h)
{
    const int i = blockIdx.x * 256 + threadIdx.x;
    const int m = i >> 7;
    const int j4 = (i & 127) * 4;
    const float* p = P + (size_t)m * 1536 + j4;
    float4 gi = *(const float4*)p;
    float4 gg = *(const float4*)(p + 512);
    float4 go = *(const float4*)(p + 1024);
    float4 r;
    r.x = fast_sigmoid(go.x) * fast_tanh(fast_sigmoid(gi.x) * fast_tanh(gg.x));
    r.y = fast_sigmoid(go.y) * fast_tanh(fast_sigmoid(gi.y) * fast_tanh(gg.y));
    r.z = fast_sigmoid(go.z) * fast_tanh(fast_sigmoid(gi.z) * fast_tanh(gg.z));
    r.w = fast_sigmoid(go.w) * fast_tanh(fast_sigmoid(gi.w) * fast_tanh(gg.w));
    *(float4*)&h[(size_t)m * 512 + j4] = r;
}

// ---------------------------------------------------------------------------
// Row-major bf16 weight pack for phase-B MFMA B-fragments (validated R17).
// ---------------------------------------------------------------------------
__global__ __launch_bounds__(256) void pack_bf16_kernel(
    const float* __restrict__ Wm, const float* __restrict__ W3,
    unsigned* __restrict__ WmB, unsigned* __restrict__ W3B)
{
    int i = blockIdx.x * 256 + threadIdx.x;           // 0 .. 524287
    if (i < 512 * 256) {
        int r = i >> 8, c = (i & 255) * 2;
        unsigned lo = f2bf(Wm[(size_t)r * 512 + c]);
        unsigned hi = f2bf(Wm[(size_t)r * 512 + c + 1]);
        WmB[(size_t)r * 256 + (c >> 1)] = lo | (hi << 16);
    } else {
        i -= 512 * 256;
        int r = i >> 8, c = (i & 255) * 2;
        int gate = r >> 9;
        int src  = (gate == 0 ? 0 : (gate == 1 ? 1024 : 1536)) + (r & 511);
        unsigned lo = f2bf(W3[(size_t)src * 1024 + c]);
        unsigned hi = f2bf(W3[(size_t)src * 1024 + c + 1]);
        W3B[(size_t)r * 256 + (c >> 1)] = lo | (hi << 16);
    }
}

// ---------------------------------------------------------------------------
// Phase B (Round 18): R17 MFMA GEMVs + #pragma unroll 1 spill fix.
//   Broadcast-A MFMA (verified R17): all 16 A-rows carry the activation,
//   C col = lane&15, read reg 0. Weights row-major bf16, 16B/lane B-frags.
//   k0/t loops pinned to unroll 1: live set ~25 VGPR, under the 64-VGPR
//   cap of 1024-thread blocks. Latency hiding = 16 resident waves (R16).
// ---------------------------------------------------------------------------
__global__ __launch_bounds__(1024) void phaseB_kernel(
    const float* __restrict__ pre_s, const float* __restrict__ pre_t,
    const float* __restrict__ h_s,   const float* __restrict__ pre_m_h,
    const unsigned* __restrict__ WmB, const unsigned* __restrict__ W3B,
    const float* __restrict__ w_e,
    const float* __restrict__ fc_w,  const float* __restrict__ fc_b,
    float* __restrict__ out)
{
    __shared__ __align__(16) float hm[512];
    __shared__ __align__(16) float base[512];
    __shared__ __align__(16) float wesh[512];
    __shared__ __align__(16) float sc[64];
    __shared__ __align__(16) float red[2 * 512];
    __shared__ __align__(16) float gates3[1536];
    __shared__ __align__(16) unsigned short hmh[512];
    __shared__ __align__(16) unsigned short hml[512];
    __shared__ __align__(16) unsigned short avh[512];
    __shared__ __align__(16) unsigned short avl[512];

    const int b    = blockIdx.x;
    const int tid  = threadIdx.x;
    const int wv   = tid >> 6;
    const int lane = tid & 63;
    const int j    = tid & 511;
    const int kh   = tid >> 9;
    const int col  = lane & 15;
    const int quad = lane >> 4;

    if (tid < 512) {
        wesh[tid] = w_e[tid];
        hm[tid] = 0.0f; hmh[tid] = 0; hml[tid] = 0;
    }
    __syncthreads();

    for (int k = 0; k < 64; ++k) {
        // ---- GEMV1: base = pre_t[k,b,:] + Wm . hm  (hm==0 at k==0: acc=0)
#pragma unroll 1
        for (int t = 0; t < 2; ++t) {
            const int nt = wv * 2 + t;                 // 0..31
            ffrag acc = {0.0f, 0.0f, 0.0f, 0.0f};
            const unsigned* wrow = WmB + (size_t)(nt * 16 + col) * 256;
#pragma unroll 1
            for (int k0 = 0; k0 < 512; k0 += 32) {
                bfrag ah = *(const bfrag*)&hmh[k0 + quad * 8];
                bfrag al = *(const bfrag*)&hml[k0 + quad * 8];
                bfrag wb = *(const bfrag*)(wrow + (k0 >> 1) + quad * 4);
                acc = __builtin_amdgcn_mfma_f32_16x16x32_bf16(ah, wb, acc, 0, 0, 0);
                acc = __builtin_amdgcn_mfma_f32_16x16x32_bf16(al, wb, acc, 0, 0, 0);
            }
            if (lane < 16)
                base[nt * 16 + lane] = acc[0]
                    + ntload(&pre_t[((size_t)k * 128 + b) * 512 + nt * 16 + lane]);
        }
        __syncthreads();

        // ---- attention scores: e[t] = w_e . tanh(pre_s[t] + base)
#pragma unroll
        for (int tt = 0; tt < 4; ++tt) {
            int t = wv * 4 + tt;
            const float* ps = pre_s + ((size_t)t * 128 + b) * 512;
            float p = 0.0f;
#pragma unroll
            for (int u = 0; u < 8; ++u) {
                int h = lane + 64 * u;
                p += wesh[h] * fast_tanh(ntload(&ps[h]) + base[h]);
            }
#pragma unroll
            for (int off = 32; off; off >>= 1) p += __shfl_xor(p, off);
            if (lane == 0) sc[t] = p;
        }
        __syncthreads();

        // ---- softmax over 64 premise positions
        if (wv == 0) {
            float s = sc[lane], mx = s;
#pragma unroll
            for (int off = 32; off; off >>= 1) mx = fmaxf(mx, __shfl_xor(mx, off));
            float e = __expf(s - mx), sum = e;
#pragma unroll
            for (int off = 32; off; off >>= 1) sum += __shfl_xor(sum, off);
            sc[lane] = e / sum;
        }
        __syncthreads();

        // ---- a_k = sum_t alpha[t] * h_s[t,b,:]   (kh-split + LDS reduce)
        {
            const float* hp = h_s + (size_t)b * 512 + j;
            float p = 0.0f;
#pragma unroll
            for (int t4 = 0; t4 < 8; ++t4) {
                int t = kh * 32 + t4 * 4;
                float4 s4 = *(const float4*)&sc[t];
                p += s4.x * ntload(&hp[(size_t)(t + 0) * 65536])
                   + s4.y * ntload(&hp[(size_t)(t + 1) * 65536])
                   + s4.z * ntload(&hp[(size_t)(t + 2) * 65536])
                   + s4.w * ntload(&hp[(size_t)(t + 3) * 65536]);
            }
            red[kh * 512 + j] = p;
        }
        __syncthreads();
        if (tid < 512) {
            float a = red[tid] + red[512 + tid];
            unsigned h = f2bf(a);
            avh[tid] = (unsigned short)h;
            avl[tid] = (unsigned short)f2bf(a - blo(h));
        }
        __syncthreads();

        // ---- GEMV2: gates3[1536] = W3 . a_k
#pragma unroll 1
        for (int t = 0; t < 6; ++t) {
            const int nt = wv * 6 + t;                 // 0..95
            ffrag acc = {0.0f, 0.0f, 0.0f, 0.0f};
            const unsigned* wrow = W3B + (size_t)(nt * 16 + col) * 256;
#pragma unroll 1
            for (int k0 = 0; k0 < 512; k0 += 32) {
                bfrag ah = *(const bfrag*)&avh[k0 + quad * 8];
                bfrag al = *(const bfrag*)&avl[k0 + quad * 8];
                bfrag wb = *(const bfrag*)(wrow + (k0 >> 1) + quad * 4);
                acc = __builtin_amdgcn_mfma_f32_16x16x32_bf16(ah, wb, acc, 0, 0, 0);
                acc = __builtin_amdgcn_mfma_f32_16x16x32_bf16(al, wb, acc, 0, 0, 0);
            }
            if (lane < 16) gates3[nt * 16 + lane] = acc[0];
        }
        __syncthreads();

        // ---- gate math -> hm (+ hi/lo pack for next step's GEMV1)
        if (tid < 512) {
            const size_t m = (size_t)k * 128 + b;
            float gi = gates3[tid]        + ntload(&pre_m_h[(m * 3 + 0) * 512 + tid]);
            float gg = gates3[512 + tid]  + ntload(&pre_m_h[(m * 3 + 1) * 512 + tid]);
            float go = gates3[1024 + tid] + ntload(&pre_m_h[(m * 3 + 2) * 512 + tid]);
            float cc = fast_sigmoid(gi) * fast_tanh(gg);
            float hv = fast_sigmoid(go) * fast_tanh(cc);
            hm[tid] = hv;
            unsigned hb = f2bf(hv);
            hmh[tid] = (unsigned short)hb;
            hml[tid] = (unsigned short)f2bf(hv - blo(hb));
        }
        __syncthreads();
    }

    if (wv < 3) {
        float p = 0.0f;
#pragma unroll
        for (int u = 0; u < 8; ++u) {
            int h = lane + 64 * u;
            p += hm[h] * fc_w[wv * 512 + h];
        }
#pragma unroll
        for (int off = 32; off; off >>= 1) p += __shfl_xor(p, off);
        if (lane == 0) out[b * 3 + wv] = p + fc_b[wv];
    }
}

extern "C" void kernel_launch(void* const* d_in, const int* in_sizes, int n_in,
                              void* d_out, int out_size, void* d_ws, size_t ws_size,
                              hipStream_t stream)
{
    (void)in_sizes; (void)n_in; (void)out_size;
    const int*   premise    = (const int*)d_in[0];
    const int*   hypothesis = (const int*)d_in[2];
    const float* embed  = (const float*)d_in[4];
    const float* w_e    = (const float*)d_in[5];
    const float* Ws     = (const float*)d_in[6];
    const float* Wt     = (const float*)d_in[7];
    const float* Wm     = (const float*)d_in[8];
    const float* Wih_p  = (const float*)d_in[9];
    const float* bih_p  = (const float*)d_in[10];
    const float* bhh_p  = (const float*)d_in[11];
    const float* Wih_h  = (const float*)d_in[12];
    const float* bih_h  = (const float*)d_in[13];
    const float* bhh_h  = (const float*)d_in[14];
    const float* Wih_m  = (const float*)d_in[15];
    const float* bih_m  = (const float*)d_in[16];
    const float* bhh_m  = (const float*)d_in[17];
    const float* fc_w   = (const float*)d_in[18];
    const float* fc_b   = (const float*)d_in[19];

    float* ws      = (float*)d_ws;
    float* h_s     = ws;                      // 8192*512
    float* h_t     = h_s    + 4194304;        // 8192*512 (aliased by packs)
    float* pre_s   = h_t    + 4194304;
    float* pre_t   = pre_s  + 4194304;
    float* pre_m_h = pre_t  + 4194304;        // 8192*3*512 (+ encoder scratch)
    unsigned* WmB  = (unsigned*)h_t;          // aliases h_t after last reader
    unsigned* W3B  = WmB + 131072;            // 512KB + 1.5MB << 16MB region
    float* outp    = (float*)d_out;
    if (ws_size < (size_t)29556736 * 4) return;

    dim3 blk(256);
    float* P = pre_m_h;                       // encoder preact scratch

    // Phase A (all MFMA, validated)
    mfma_g3_kernel<1><<<dim3(128, 24), blk, 0, stream>>>(
        embed, premise, 300, 300, Wih_p, 300, bih_p, bhh_p, P);
    enc_gates_kernel<<<4096, blk, 0, stream>>>(P, h_s);
    mfma_g3_kernel<1><<<dim3(128, 24), blk, 0, stream>>>(
        embed, hypothesis, 300, 300, Wih_h, 300, bih_h, bhh_h, P);
    enc_gates_kernel<<<4096, blk, 0, stream>>>(P, h_t);
    mfma_nt_kernel<<<dim3(128, 8), blk, 0, stream>>>(h_s, Ws, pre_s);
    mfma_nt_kernel<<<dim3(128, 8), blk, 0, stream>>>(h_t, Wt, pre_t);
    mfma_g3_kernel<0><<<dim3(128, 24), blk, 0, stream>>>(
        h_t, nullptr, 512, 512, Wih_m + 512, 1024, bih_m, bhh_m, pre_m_h);

    // Weight pack (after h_t's last reader; output aliases h_t space)
    pack_bf16_kernel<<<2048, blk, 0, stream>>>(Wm, Wih_m, WmB, W3B);

    // Phase B (MFMA GEMVs, spill-fixed)
    phaseB_kernel<<<dim3(128), dim3(1024), 0, stream>>>(
        pre_s, pre_t, h_s, pre_m_h, WmB, W3B, w_e, fc_w, fc_b, outp);
}

// Round 4
// 2057.441 us; speedup vs baseline: 4.8714x; 2.2809x over previous
//
#include <hip/hip_runtime.h>

// MatchLSTM forward (Round 19): phase-B GEMV latency fix.
//   R18 post-mortem: spills gone (WRITE 5KB) but MfmaUtil 5.5 / VALU 7.2 ->
//   pure latency-bound: unroll-1 iters serialize {1 L2 load -> vmcnt(0) ->
//   2 dep MFMAs} with only 4 waves/SIMD. R19:
//   (a) hi/lo in A-ROWS (rows 0-7 hi, 8-15 lo; sum C[0]+C[8] via shfl_xor 32)
//       -> 1 MFMA per weight-frag instead of 2 (2048/block/step, 4.1 us floor)
//   (b) k-outer/tile-inner, 2-3 independent acc+load chains per iter -> MLP
//   (c) weight pack re-laid out [kc][tile][lane] -> one running pointer,
//       imm offsets 0/1024/2048, 1KB coalesced wave-loads, ~40 VGPR live.
// Phase A: Round-15 verbatim (validated).

#define DEV static __device__ __forceinline__

DEV float fast_sigmoid(float x) { return 1.0f / (1.0f + __expf(-x)); }
DEV float fast_tanh(float x)    { return 1.0f - 2.0f / (__expf(2.0f * x) + 1.0f); }

DEV unsigned f2bf(float x) {
    unsigned v = __float_as_uint(x);
    return (v + 0x7FFFu + ((v >> 16) & 1u)) >> 16;
}
DEV float blo(unsigned u) { return __uint_as_float(u << 16); }

DEV float ntload(const float* p) { return __builtin_nontemporal_load(p); }

typedef __attribute__((ext_vector_type(8))) short bfrag;   // 8 bf16
typedef __attribute__((ext_vector_type(4))) float ffrag;   // 4 fp32 acc

DEV void cvt_hilo(const float* v, bfrag& hi, bfrag& lo)
{
#pragma unroll
    for (int z = 0; z < 8; ++z) {
        unsigned h = f2bf(v[z]);
        hi[z] = (short)h;
        lo[z] = (short)f2bf(v[z] - __uint_as_float(h << 16));
    }
}

// ---------------------------------------------------------------------------
// MFMA GEMM (validated R14): C[M][512] = A[M][512] . W[512][512]^T, bf16x3.
// ---------------------------------------------------------------------------
__global__ __launch_bounds__(256) void mfma_nt_kernel(
    const float* __restrict__ A, const float* __restrict__ W,
    float* __restrict__ C)
{
    const int wv   = threadIdx.x >> 6;
    const int lane = threadIdx.x & 63;
    const int row  = lane & 15;
    const int quad = lane >> 4;
    const int m0 = blockIdx.x * 64 + wv * 16;
    const int n0 = blockIdx.y * 64;

    ffrag acc[4];
#pragma unroll
    for (int n = 0; n < 4; ++n)
#pragma unroll
        for (int r = 0; r < 4; ++r) acc[n][r] = 0.0f;

    for (int k0 = 0; k0 < 512; k0 += 32) {
        const float* ap = A + (size_t)(m0 + row) * 512 + k0 + quad * 8;
        float4 aA = *(const float4*)ap;
        float4 aB = *(const float4*)(ap + 4);
        float av[8] = {aA.x, aA.y, aA.z, aA.w, aB.x, aB.y, aB.z, aB.w};
        bfrag ahi, alo;
        cvt_hilo(av, ahi, alo);
#pragma unroll
        for (int n = 0; n < 4; ++n) {
            const float* wp = W + (size_t)(n0 + n * 16 + row) * 512 + k0 + quad * 8;
            float4 wA = *(const float4*)wp;
            float4 wB = *(const float4*)(wp + 4);
            float wvv[8] = {wA.x, wA.y, wA.z, wA.w, wB.x, wB.y, wB.z, wB.w};
            bfrag whi, wlo;
            cvt_hilo(wvv, whi, wlo);
            acc[n] = __builtin_amdgcn_mfma_f32_16x16x32_bf16(ahi, whi, acc[n], 0, 0, 0);
            acc[n] = __builtin_amdgcn_mfma_f32_16x16x32_bf16(alo, whi, acc[n], 0, 0, 0);
            acc[n] = __builtin_amdgcn_mfma_f32_16x16x32_bf16(ahi, wlo, acc[n], 0, 0, 0);
        }
    }
#pragma unroll
    for (int n = 0; n < 4; ++n)
#pragma unroll
        for (int r = 0; r < 4; ++r)
            C[(size_t)(m0 + quad * 4 + r) * 512 + n0 + n * 16 + row] = acc[n][r];
}

// ---------------------------------------------------------------------------
// 3-gate MFMA GEMM (validated R15).
// ---------------------------------------------------------------------------
template<int GATHER>
__global__ __launch_bounds__(256) void mfma_g3_kernel(
    const float* __restrict__ A, const int* __restrict__ gidx,
    int lda, int K,
    const float* __restrict__ W, int ldw,
    const float* __restrict__ bias1, const float* __restrict__ bias2,
    float* __restrict__ out)
{
    const int wv   = threadIdx.x >> 6;
    const int lane = threadIdx.x & 63;
    const int row  = lane & 15;
    const int quad = lane >> 4;
    const int m0   = blockIdx.x * 64 + wv * 16;
    const int gate = blockIdx.y >> 3;
    const int gbase = (gate == 0) ? 0 : (gate == 1 ? 1024 : 1536);
    const int j0   = (blockIdx.y & 7) * 64;

    const int arow = GATHER ? gidx[m0 + row] : (m0 + row);

    ffrag acc[4];
#pragma unroll
    for (int n = 0; n < 4; ++n)
#pragma unroll
        for (int r = 0; r < 4; ++r) acc[n][r] = 0.0f;

    for (int k0 = 0; k0 < K; k0 += 32) {
        const bool tail = (k0 + 32 > K);
        float av[8];
        if (!tail) {
            const float* ap = A + (size_t)arow * lda + k0 + quad * 8;
            float4 aA = *(const float4*)ap;
            float4 aB = *(const float4*)(ap + 4);
            av[0]=aA.x; av[1]=aA.y; av[2]=aA.z; av[3]=aA.w;
            av[4]=aB.x; av[5]=aB.y; av[6]=aB.z; av[7]=aB.w;
        } else {
#pragma unroll
            for (int z = 0; z < 8; ++z) {
                int kk = k0 + quad * 8 + z;
                av[z] = (kk < K) ? A[(size_t)arow * lda + kk] : 0.0f;
            }
        }
        bfrag ahi, alo;
        cvt_hilo(av, ahi, alo);
#pragma unroll
        for (int n = 0; n < 4; ++n) {
            const int wrow = gbase + j0 + n * 16 + row;
            float wvv[8];
            if (!tail) {
                const float* wp = W + (size_t)wrow * ldw + k0 + quad * 8;
                float4 wA = *(const float4*)wp;
                float4 wB = *(const float4*)(wp + 4);
                wvv[0]=wA.x; wvv[1]=wA.y; wvv[2]=wA.z; wvv[3]=wA.w;
                wvv[4]=wB.x; wvv[5]=wB.y; wvv[6]=wB.z; wvv[7]=wB.w;
            } else {
#pragma unroll
                for (int z = 0; z < 8; ++z) {
                    int kk = k0 + quad * 8 + z;
                    wvv[z] = (kk < K) ? W[(size_t)wrow * ldw + kk] : 0.0f;
                }
            }
            bfrag whi, wlo;
            cvt_hilo(wvv, whi, wlo);
            acc[n] = __builtin_amdgcn_mfma_f32_16x16x32_bf16(ahi, whi, acc[n], 0, 0, 0);
            acc[n] = __builtin_amdgcn_mfma_f32_16x16x32_bf16(alo, whi, acc[n], 0, 0, 0);
            acc[n] = __builtin_amdgcn_mfma_f32_16x16x32_bf16(ahi, wlo, acc[n], 0, 0, 0);
        }
    }
#pragma unroll
    for (int n = 0; n < 4; ++n) {
        const int j = j0 + n * 16 + row;
        const float bb = bias1[gbase + j] + bias2[gbase + j];
#pragma unroll
        for (int r = 0; r < 4; ++r) {
            const int m = m0 + quad * 4 + r;
            out[((size_t)m * 3 + gate) * 512 + j] = acc[n][r] + bb;
        }
    }
}

// ---------------------------------------------------------------------------
// Encoder gate math (validated R15).
// ---------------------------------------------------------------------------
__global__ __launch_bounds__(256) void enc_gates_kernel(
    const float* __restrict__ P, float* __restrict__ h)
{
    const int i = blockIdx.x * 256 + threadIdx.x;
    const int m = i >> 7;
    const int j4 = (i & 127) * 4;
    const float* p = P + (size_t)m * 1536 + j4;
    float4 gi = *(const float4*)p;
    float4 gg = *(const float4*)(p + 512);
    float4 go = *(const float4*)(p + 1024);
    float4 r;
    r.x = fast_sigmoid(go.x) * fast_tanh(fast_sigmoid(gi.x) * fast_tanh(gg.x));
    r.y = fast_sigmoid(go.y) * fast_tanh(fast_sigmoid(gi.y) * fast_tanh(gg.y));
    r.z = fast_sigmoid(go.z) * fast_tanh(fast_sigmoid(gi.z) * fast_tanh(gg.z));
    r.w = fast_sigmoid(go.w) * fast_tanh(fast_sigmoid(gi.w) * fast_tanh(gg.w));
    *(float4*)&h[(size_t)m * 512 + j4] = r;
}

// ---------------------------------------------------------------------------
// Weight pack, tile-interleaved layout for phase-B (R19).
//   uint4 index q = (kc*NT + nt)*64 + lane  holds the B-frag of
//   (row = nt*16 + (lane&15), k = kc*32 + (lane>>4)*8 .. +8) as 8 bf16.
//   WmB: NT=32 (Wm 512x512). W3B: NT=96 (Wih_m a_k-half rows i/g/o).
//   Same fragment CONTENT as the validated R17 per-row pack, new addressing.
// ---------------------------------------------------------------------------
__global__ __launch_bounds__(256) void pack_bf16_kernel(
    const float* __restrict__ Wm, const float* __restrict__ W3,
    unsigned* __restrict__ WmB, unsigned* __restrict__ W3B)
{
    int i = blockIdx.x * 256 + threadIdx.x;           // 0 .. 524287
    if (i < 131072) {                                  // Wm: 16*32*64*4
        int u = i & 3, lane = (i >> 2) & 63;
        int nt = (i >> 8) & 31, kc = i >> 13;
        int row = nt * 16 + (lane & 15);
        int k = kc * 32 + ((lane >> 4) << 3) + u * 2;
        unsigned lo = f2bf(Wm[(size_t)row * 512 + k]);
        unsigned hi = f2bf(Wm[(size_t)row * 512 + k + 1]);
        WmB[i] = lo | (hi << 16);
    } else {                                           // W3: 16*96*64*4
        int j = i - 131072;
        int u = j & 3, lane = (j >> 2) & 63;
        int blk = j >> 8;                              // kc*96 + nt
        int kc = blk / 96, nt = blk - kc * 96;
        int row = nt * 16 + (lane & 15);               // 0..1535
        int gate = row >> 9;
        int src  = (gate == 0 ? 0 : (gate == 1 ? 1024 : 1536)) + (row & 511);
        int k = kc * 32 + ((lane >> 4) << 3) + u * 2;
        unsigned lo = f2bf(W3[(size_t)src * 1024 + k]);
        unsigned hi = f2bf(W3[(size_t)src * 1024 + k + 1]);
        W3B[j] = lo | (hi << 16);
    }
}

// ---------------------------------------------------------------------------
// Phase B (Round 19): MFMA GEMVs, latency-tolerant form.
//   hi/lo packed into A-ROWS: lane row<8 loads hi vector, row>=8 lo vector;
//   C[row] + C[row^8-group] summed via __shfl_xor(.,32) (quad0+quad2 etc).
//   k-outer / tile-inner: 2 (GEMV1) or 3 (GEMV2 x2 passes) independent
//   acc chains + weight loads in flight per iteration.
// ---------------------------------------------------------------------------
__global__ __launch_bounds__(1024) void phaseB_kernel(
    const float* __restrict__ pre_s, const float* __restrict__ pre_t,
    const float* __restrict__ h_s,   const float* __restrict__ pre_m_h,
    const unsigned* __restrict__ WmB, const unsigned* __restrict__ W3B,
    const float* __restrict__ w_e,
    const float* __restrict__ fc_w,  const float* __restrict__ fc_b,
    float* __restrict__ out)
{
    __shared__ __align__(16) float hm[512];
    __shared__ __align__(16) float base[512];
    __shared__ __align__(16) float wesh[512];
    __shared__ __align__(16) float sc[64];
    __shared__ __align__(16) float red[2 * 512];
    __shared__ __align__(16) float gates3[1536];
    __shared__ __align__(16) unsigned short hmh[512];
    __shared__ __align__(16) unsigned short hml[512];
    __shared__ __align__(16) unsigned short avh[512];
    __shared__ __align__(16) unsigned short avl[512];

    const int b    = blockIdx.x;
    const int tid  = threadIdx.x;
    const int wv   = tid >> 6;
    const int lane = tid & 63;
    const int j    = tid & 511;
    const int kh   = tid >> 9;
    const int quad = lane >> 4;

    if (tid < 512) {
        wesh[tid] = w_e[tid];
        hm[tid] = 0.0f; hmh[tid] = 0; hml[tid] = 0;
    }
    __syncthreads();

    for (int k = 0; k < 64; ++k) {
        // ---- GEMV1: base = pre_t[k,b,:] + Wm . hm
        {
            ffrag acc0 = {0.0f, 0.0f, 0.0f, 0.0f};
            ffrag acc1 = {0.0f, 0.0f, 0.0f, 0.0f};
            const uint4* wp = (const uint4*)WmB + (size_t)(wv * 2) * 64 + lane;
            const unsigned short* ab = ((lane & 8) == 0) ? hmh : hml;
#pragma unroll 1
            for (int kc = 0; kc < 16; ++kc) {
                bfrag a  = *(const bfrag*)&ab[kc * 32 + quad * 8];
                bfrag w0 = *(const bfrag*)(wp);
                bfrag w1 = *(const bfrag*)(wp + 64);
                acc0 = __builtin_amdgcn_mfma_f32_16x16x32_bf16(a, w0, acc0, 0, 0, 0);
                acc1 = __builtin_amdgcn_mfma_f32_16x16x32_bf16(a, w1, acc1, 0, 0, 0);
                wp += 2048;                            // next kc (32 tiles * 64)
            }
            float s0 = acc0[0] + __shfl_xor(acc0[0], 32);
            float s1 = acc1[0] + __shfl_xor(acc1[0], 32);
            if (lane < 32) {
                int c = lane & 15, t = lane >> 4;
                int nt = wv * 2 + t;
                float v = t ? s1 : s0;
                base[nt * 16 + c] = v
                    + ntload(&pre_t[((size_t)k * 128 + b) * 512 + nt * 16 + c]);
            }
        }
        __syncthreads();

        // ---- attention scores: e[t] = w_e . tanh(pre_s[t] + base)
#pragma unroll
        for (int tt = 0; tt < 4; ++tt) {
            int t = wv * 4 + tt;
            const float* ps = pre_s + ((size_t)t * 128 + b) * 512;
            float p = 0.0f;
#pragma unroll
            for (int u = 0; u < 8; ++u) {
                int h = lane + 64 * u;
                p += wesh[h] * fast_tanh(ntload(&ps[h]) + base[h]);
            }
#pragma unroll
            for (int off = 32; off; off >>= 1) p += __shfl_xor(p, off);
            if (lane == 0) sc[t] = p;
        }
        __syncthreads();

        // ---- softmax over 64 premise positions
        if (wv == 0) {
            float s = sc[lane], mx = s;
#pragma unroll
            for (int off = 32; off; off >>= 1) mx = fmaxf(mx, __shfl_xor(mx, off));
            float e = __expf(s - mx), sum = e;
#pragma unroll
            for (int off = 32; off; off >>= 1) sum += __shfl_xor(sum, off);
            sc[lane] = e / sum;
        }
        __syncthreads();

        // ---- a_k = sum_t alpha[t] * h_s[t,b,:]   (kh-split + LDS reduce)
        {
            const float* hp = h_s + (size_t)b * 512 + j;
            float p = 0.0f;
#pragma unroll
            for (int t4 = 0; t4 < 8; ++t4) {
                int t = kh * 32 + t4 * 4;
                float4 s4 = *(const float4*)&sc[t];
                p += s4.x * ntload(&hp[(size_t)(t + 0) * 65536])
                   + s4.y * ntload(&hp[(size_t)(t + 1) * 65536])
                   + s4.z * ntload(&hp[(size_t)(t + 2) * 65536])
                   + s4.w * ntload(&hp[(size_t)(t + 3) * 65536]);
            }
            red[kh * 512 + j] = p;
        }
        __syncthreads();
        if (tid < 512) {
            float a = red[tid] + red[512 + tid];
            unsigned h = f2bf(a);
            avh[tid] = (unsigned short)h;
            avl[tid] = (unsigned short)f2bf(a - blo(h));
        }
        __syncthreads();

        // ---- GEMV2: gates3[1536] = W3 . a_k   (2 passes x 3 tiles/wave)
#pragma unroll 1
        for (int p3 = 0; p3 < 2; ++p3) {
            ffrag a0 = {0.0f, 0.0f, 0.0f, 0.0f};
            ffrag a1 = {0.0f, 0.0f, 0.0f, 0.0f};
            ffrag a2 = {0.0f, 0.0f, 0.0f, 0.0f};
            const uint4* wp = (const uint4*)W3B
                            + (size_t)(wv * 6 + p3 * 3) * 64 + lane;
            const unsigned short* ab = ((lane & 8) == 0) ? avh : avl;
#pragma unroll 1
            for (int kc = 0; kc < 16; ++kc) {
                bfrag a  = *(const bfrag*)&ab[kc * 32 + quad * 8];
                bfrag w0 = *(const bfrag*)(wp);
                bfrag w1 = *(const bfrag*)(wp + 64);
                bfrag w2 = *(const bfrag*)(wp + 128);
                a0 = __builtin_amdgcn_mfma_f32_16x16x32_bf16(a, w0, a0, 0, 0, 0);
                a1 = __builtin_amdgcn_mfma_f32_16x16x32_bf16(a, w1, a1, 0, 0, 0);
                a2 = __builtin_amdgcn_mfma_f32_16x16x32_bf16(a, w2, a2, 0, 0, 0);
                wp += 6144;                            // next kc (96 tiles * 64)
            }
            float s0 = a0[0] + __shfl_xor(a0[0], 32);
            float s1 = a1[0] + __shfl_xor(a1[0], 32);
            float s2 = a2[0] + __shfl_xor(a2[0], 32);
            if (lane < 48) {
                int c = lane & 15, i = lane >> 4;
                float v = (i == 0) ? s0 : (i == 1 ? s1 : s2);
                gates3[(wv * 6 + p3 * 3 + i) * 16 + c] = v;
            }
        }
        __syncthreads();

        // ---- gate math -> hm (+ hi/lo pack for next step's GEMV1)
        if (tid < 512) {
            const size_t m = (size_t)k * 128 + b;
            float gi = gates3[tid]        + ntload(&pre_m_h[(m * 3 + 0) * 512 + tid]);
            float gg = gates3[512 + tid]  + ntload(&pre_m_h[(m * 3 + 1) * 512 + tid]);
            float go = gates3[1024 + tid] + ntload(&pre_m_h[(m * 3 + 2) * 512 + tid]);
            float cc = fast_sigmoid(gi) * fast_tanh(gg);
            float hv = fast_sigmoid(go) * fast_tanh(cc);
            hm[tid] = hv;
            unsigned hb = f2bf(hv);
            hmh[tid] = (unsigned short)hb;
            hml[tid] = (unsigned short)f2bf(hv - blo(hb));
        }
        __syncthreads();
    }

    if (wv < 3) {
        float p = 0.0f;
#pragma unroll
        for (int u = 0; u < 8; ++u) {
            int h = lane + 64 * u;
            p += hm[h] * fc_w[wv * 512 + h];
        }
#pragma unroll
        for (int off = 32; off; off >>= 1) p += __shfl_xor(p, off);
        if (lane == 0) out[b * 3 + wv] = p + fc_b[wv];
    }
}

extern "C" void kernel_launch(void* const* d_in, const int* in_sizes, int n_in,
                              void* d_out, int out_size, void* d_ws, size_t ws_size,
                              hipStream_t stream)
{
    (void)in_sizes; (void)n_in; (void)out_size;
    const int*   premise    = (const int*)d_in[0];
    const int*   hypothesis = (const int*)d_in[2];
    const float* embed  = (const float*)d_in[4];
    const float* w_e    = (const float*)d_in[5];
    const float* Ws     = (const float*)d_in[6];
    const float* Wt     = (const float*)d_in[7];
    const float* Wm     = (const float*)d_in[8];
    const float* Wih_p  = (const float*)d_in[9];
    const float* bih_p  = (const float*)d_in[10];
    const float* bhh_p  = (const float*)d_in[11];
    const float* Wih_h  = (const float*)d_in[12];
    const float* bih_h  = (const float*)d_in[13];
    const float* bhh_h  = (const float*)d_in[14];
    const float* Wih_m  = (const float*)d_in[15];
    const float* bih_m  = (const float*)d_in[16];
    const float* bhh_m  = (const float*)d_in[17];
    const float* fc_w   = (const float*)d_in[18];
    const float* fc_b   = (const float*)d_in[19];

    float* ws      = (float*)d_ws;
    float* h_s     = ws;                      // 8192*512
    float* h_t     = h_s    + 4194304;        // 8192*512 (aliased by packs)
    float* pre_s   = h_t    + 4194304;
    float* pre_t   = pre_s  + 4194304;
    float* pre_m_h = pre_t  + 4194304;        // 8192*3*512 (+ encoder scratch)
    unsigned* WmB  = (unsigned*)h_t;          // aliases h_t after last reader
    unsigned* W3B  = WmB + 131072;            // 512KB + 1.5MB << 16MB region
    float* outp    = (float*)d_out;
    if (ws_size < (size_t)29556736 * 4) return;

    dim3 blk(256);
    float* P = pre_m_h;                       // encoder preact scratch

    // Phase A (all MFMA, validated)
    mfma_g3_kernel<1><<<dim3(128, 24), blk, 0, stream>>>(
        embed, premise, 300, 300, Wih_p, 300, bih_p, bhh_p, P);
    enc_gates_kernel<<<4096, blk, 0, stream>>>(P, h_s);
    mfma_g3_kernel<1><<<dim3(128, 24), blk, 0, stream>>>(
        embed, hypothesis, 300, 300, Wih_h, 300, bih_h, bhh_h, P);
    enc_gates_kernel<<<4096, blk, 0, stream>>>(P, h_t);
    mfma_nt_kernel<<<dim3(128, 8), blk, 0, stream>>>(h_s, Ws, pre_s);
    mfma_nt_kernel<<<dim3(128, 8), blk, 0, stream>>>(h_t, Wt, pre_t);
    mfma_g3_kernel<0><<<dim3(128, 24), blk, 0, stream>>>(
        h_t, nullptr, 512, 512, Wih_m + 512, 1024, bih_m, bhh_m, pre_m_h);

    // Weight pack (after h_t's last reader; output aliases h_t space)
    pack_bf16_kernel<<<2048, blk, 0, stream>>>(Wm, Wih_m, WmB, W3B);

    // Phase B (MFMA GEMVs, latency-tolerant)
    phaseB_kernel<<<dim3(128), dim3(1024), 0, stream>>>(
        pre_s, pre_t, h_s, pre_m_h, WmB, W3B, w_e, fc_w, fc_b, outp);
}